// Round 1
// baseline (256.056 us; speedup 1.0000x reference)
//
#include <hip/hip_runtime.h>

// y = x @ W^T where W is dense [N,N] but strictly diagonal.
// Exact: y[t,j] = x[t,j] * W[j,j] (off-diag terms are exact 0.0f).
//
// R4: fuse diag-gather + scale into ONE kernel via column-blocked mapping.
// Each block owns a 256-feature column slab x 32 rows, so it needs only 256
// diagonal floats: one scattered 4B load per thread -> LDS -> one nf4 in a
// register per lane, reused for all 8 rows that lane touches. This kills the
// separate 16-block compact kernel (launch + serialization bubble) and the
// workspace round-trip, while keeping every x/y wave access 1 KiB contiguous
// (64 lanes x 16 B within a single row). Scattered W traffic: 256 loads/block
// x 4096 blocks = ~67 MB of L2-hit requests (~0.5 MiB unique HBM lines),
// fully overlapped with streaming -- 16x less than the old row-major fused
// attempt that needed all 4096 diag entries per block.

typedef float nf4 __attribute__((ext_vector_type(4)));

constexpr int N_FEAT   = 4096;
constexpr int NVEC_ROW = N_FEAT / 4;   // 1024 nf4 per row
constexpr int BLOCK    = 256;
constexpr int ROWS_PB  = 32;           // rows per block
constexpr int CG       = 16;           // column groups (4096 feat / 256)
// grid = CG * (8192 / ROWS_PB) = 16 * 256 = 4096 blocks
// per block: 32 rows x 1 KiB slab = 32 KiB read + 32 KiB write

__global__ __launch_bounds__(BLOCK)
void diag_scale_fused(const float* __restrict__ W,
                      const nf4* __restrict__ x,
                      nf4* __restrict__ y) {
    const int tid  = threadIdx.x;
    const int lane = tid & 63;
    const int wave = tid >> 6;
    const int cg   = blockIdx.x & (CG - 1);   // column group: 256 features
    const int rg   = blockIdx.x >> 4;         // row group: 32 rows

    // Stage this slab's 256 diag entries: thread t fetches feature cg*256+t.
    // One scattered 4B load per thread (stride 16388 B in W); L2-hot after
    // the first block per XCD touches these lines.
    __shared__ float dsh[BLOCK];
    dsh[tid] = W[(long)(cg * BLOCK + tid) * (N_FEAT + 1)];
    __syncthreads();

    // Lane owns nf4 column cg*64+lane -> features cg*256 + 4*lane + k,
    // i.e. dsh[4*lane .. 4*lane+3] = ((nf4*)dsh)[lane]. One ds_read_b128.
    const nf4 d = ((const nf4*)dsh)[lane];

    const long col  = (long)cg * 64 + lane;            // nf4 column index
    const long row0 = (long)rg * ROWS_PB + wave * 8;   // this wave's 8 rows

    // 8-deep load clause (1 KiB contiguous per wave-load, rows stride 16 KiB),
    // then 8 multiply + cacheable stores (same coalescing).
    nf4 xv[8];
#pragma unroll
    for (int j = 0; j < 8; ++j)
        xv[j] = x[(row0 + j) * NVEC_ROW + col];

#pragma unroll
    for (int j = 0; j < 8; ++j)
        y[(row0 + j) * NVEC_ROW + col] = xv[j] * d;
}

extern "C" void kernel_launch(void* const* d_in, const int* in_sizes, int n_in,
                              void* d_out, int out_size, void* d_ws, size_t ws_size,
                              hipStream_t stream) {
    const nf4*   x = (const nf4*)d_in[0];     // [8192, 4096] f32
    const float* W = (const float*)d_in[1];   // [4096, 4096] f32, diagonal
    nf4*         y = (nf4*)d_out;             // [8192, 4096] f32

    diag_scale_fused<<<4096, BLOCK, 0, stream>>>(W, x, y);
}